// Round 2
// baseline (835.032 us; speedup 1.0000x reference)
//
#include <hip/hip_runtime.h>
#include <stdint.h>
#include <math.h>

// ---------------------------------------------------------------------------
// GraphDistillOperatorWithEdgeWeight, N=8192, F=256, OUT=256
//
//   E_ij = exp(5*adj_ij), E_ii = 0 ; s_i = sum_j E_ij ; a = E/s
//   agg = a@feat ; kagg = a@key
//   out1 = tanh(Xcat @ W1 + c1),  Xcat=[feat|agg],  W1=[[W_o],[0]] - W_d@W_o
//   out2 = tanh(Kcat @ W2 + c2),  Kcat=[key|kagg],  W2=[[W_ao],[W_a@W_ao]]
//
// Round change:
//  (1) X stored as MFMA-fragment blobs (Xtb): B-loads become single coalesced
//      1KB instructions (was 32-line row-gather per load -> latency hole).
//  (2) exp_gemm: ROWS 64, 512-thread blocks, grid 512 -> 2 barrier domains/CU;
//      launch_bounds(512,4) removes the 64-VGPR clamp (suspected spill);
//      depth-2 register double-buffer for B; setprio around MFMA cluster.
//  (3) gemm_out: back to Mtile 32 (16 doubled staging/FLOP), fused, grid 512.
// ---------------------------------------------------------------------------

typedef __attribute__((ext_vector_type(4)))  short bf16x4_t;
typedef __attribute__((ext_vector_type(8)))  short bf16x8_t;
typedef __attribute__((ext_vector_type(4)))  float f32x4_t;
typedef __attribute__((ext_vector_type(16))) float f32x16_t;

#define MFMA32(A, B, C) __builtin_amdgcn_mfma_f32_32x32x16_bf16(A, B, C, 0, 0, 0)
#define MFMA16(A, B, C) __builtin_amdgcn_mfma_f32_16x16x32_bf16(A, B, C, 0, 0, 0)

__device__ __forceinline__ unsigned short f2bf(float x) {
    union { float f; unsigned u; } c; c.f = x;
    unsigned u = c.u;
    return (unsigned short)((u + 0x7fffu + ((u >> 16) & 1u)) >> 16);  // RNE
}
__device__ __forceinline__ unsigned pack2bf(float a, float b) {
    return (unsigned)f2bf(a) | ((unsigned)f2bf(b) << 16);
}
__device__ __forceinline__ float bflo(unsigned u) {
    union { unsigned u; float f; } c; c.u = u << 16; return c.f;
}
__device__ __forceinline__ float bfhi(unsigned u) {
    union { unsigned u; float f; } c; c.u = u & 0xffff0000u; return c.f;
}

// ---------------------------------------------------------------------------
// transpose_blob: src[8192][256] f32 (row index = k) -> Xtb fragment blobs.
// Blob (j = k/32, c32): 1024 shorts, short idx = s*512 + lane*8 + e, where
// lane = ((k>>3)&1)*32 + (col&31), s = (k>>4)&1, e = k&7.  A wave's B-frag
// for (j, c32, s) is then ONE contiguous 1KB load at lane*16B.
// grid = (256 k-tiles, 8 col-tiles), block = 256.
// ---------------------------------------------------------------------------
__global__ __launch_bounds__(256) void transpose_blob(
    const float* __restrict__ src, unsigned short* __restrict__ Xtb, int c32base)
{
    __shared__ float tile[32][33];
    const int t = threadIdx.x;
    const int x = t & 31, y4 = (t >> 5) * 4;
    const int r0 = blockIdx.x * 32, c0 = blockIdx.y * 32;
#pragma unroll
    for (int i = 0; i < 4; ++i)
        tile[y4 + i][x] = src[(size_t)(r0 + y4 + i) * 256 + c0 + x];
    __syncthreads();
    // thread t writes shorts [t*4 .. t*4+3]: s = t>>7, lane = (t>>1)&63, e0 = (t&1)*4
    const int s = t >> 7, lane = (t >> 1) & 63, e0 = (t & 1) * 4;
    const int kl = s * 16 + (lane >> 5) * 8 + e0;   // k-local 0..31
    const int cl = lane & 31;                        // col-local
    unsigned short* blob = Xtb + ((size_t)blockIdx.x * 16 + (c0 >> 5) + c32base) * 1024;
    uint2 v;
    v.x = pack2bf(tile[kl][cl],     tile[kl + 1][cl]);
    v.y = pack2bf(tile[kl + 2][cl], tile[kl + 3][cl]);
    *(uint2*)(blob + t * 4) = v;
}

// dst row-major uint rows of 256 (=512 bf16 cols), fill cols 0..255.
__global__ __launch_bounds__(256) void pack_half(
    const float* __restrict__ src, unsigned* __restrict__ dst)
{
    const int idx = blockIdx.x * 256 + threadIdx.x;
    const int row = idx >> 7, cp = idx & 127;
    float2 v = *(const float2*)(src + (size_t)row * 256 + cp * 2);
    dst[(size_t)row * 256 + cp] = pack2bf(v.x, v.y);
}

// ---------------------------------------------------------------------------
// Weight composition (unchanged).
// ---------------------------------------------------------------------------
__global__ __launch_bounds__(256) void compose1(
    const float* __restrict__ W_d, const float* __restrict__ W_o,
    unsigned short* __restrict__ W1t)
{
    __shared__ float wrow[256];
    const int k = blockIdx.x, t = threadIdx.x;
    wrow[t] = W_d[(size_t)k * 256 + t];
    __syncthreads();
    float acc = 0.f;
#pragma unroll 8
    for (int m = 0; m < 256; ++m) acc = fmaf(wrow[m], W_o[(size_t)m * 256 + t], acc);
    const float v = (k < 256 ? W_o[(size_t)k * 256 + t] : 0.f) - acc;
    W1t[(size_t)t * 512 + k] = f2bf(v);
}

__global__ __launch_bounds__(256) void compose2(
    const float* __restrict__ W_a, const float* __restrict__ W_ao,
    unsigned short* __restrict__ W2t)
{
    __shared__ float wrow[256];
    const int k = blockIdx.x, t = threadIdx.x;
    float v;
    if (k < 256) {
        v = W_ao[(size_t)k * 256 + t];
    } else {
        wrow[t] = W_a[(size_t)(k - 256) * 256 + t];
        __syncthreads();
        float acc = 0.f;
#pragma unroll 8
        for (int m = 0; m < 256; ++m) acc = fmaf(wrow[m], W_ao[(size_t)m * 256 + t], acc);
        v = acc;
    }
    W2t[(size_t)t * 512 + k] = f2bf(v);
}

__global__ __launch_bounds__(256) void biasC(
    const float* __restrict__ b_d, const float* __restrict__ b_o,
    const float* __restrict__ b_a, const float* __restrict__ b_ao,
    const float* __restrict__ W_o, const float* __restrict__ W_ao,
    float* __restrict__ c1, float* __restrict__ c2)
{
    const int t = threadIdx.x;
    float a1 = 0.f, a2 = 0.f;
#pragma unroll 8
    for (int m = 0; m < 256; ++m) {
        a1 = fmaf(b_d[m], W_o [(size_t)m * 256 + t], a1);
        a2 = fmaf(b_a[m], W_ao[(size_t)m * 256 + t], a2);
    }
    c1[t] = b_o[t] - a1;
    c2[t] = b_ao[t] + a2;
}

// ---------------------------------------------------------------------------
// exp_gemm: Upart[h] = bf16( E_slice @ [feat|key] ), rowsum partials f32.
// grid = 512 (128 rowblocks x 4 K-split), block = 512 (8 waves).
// Block tile: 64 rows x 512 cols, K-slice 2048. Wave: 64 rows x 64 cols
// (2 mt x 2 ct of 32x32). LDS 36 KB -> 2 blocks/CU (2 barrier domains).
// B from Xtb blobs: one coalesced 1KB load per fragment, depth-2 reg dbuf.
// ---------------------------------------------------------------------------
#define ROWS 64
#define KSLICE 2048
#define NIT 64      // k-steps of 32 per K-slice
#define NCH 16      // chunks of 4 k-steps
#define ASTRIDE 36  // padded LDS row stride (shorts)

__global__ __launch_bounds__(512, 4) void exp_gemm(
    const float* __restrict__ adj, const unsigned short* __restrict__ Xtb,
    unsigned* __restrict__ UpartB, float* __restrict__ sSp)
{
    __shared__ unsigned short sA[2][4][ROWS * ASTRIDE];  // 36 KB

    const int t = threadIdx.x;
    const int w = t >> 6, lane = t & 63, q = lane >> 5, l31 = lane & 31;
    const int rb = blockIdx.x >> 2, h = blockIdx.x & 3;  // h fixed per XCD (bid%8)
    const int row0 = rb * ROWS;
    const int kbase = h * KSLICE, jbase = h * (KSLICE / 32);

    // stager role: row srow (t>>3, 0..63), k-offset skoff (8 threads/row)
    const int srow = t >> 3, skoff = (t & 7) * 4;
    const int sgrow = row0 + srow;
    const float* adj_row = adj + (size_t)sgrow * 8192 + kbase + skoff;
    const int swoff = srow * ASTRIDE + skoff;

    // wave w owns cols w*64..w*64+63 (c32 = 2w, 2w+1)
    const unsigned short* wb = Xtb + (size_t)(2 * w) * 1024 + lane * 8;

    float rs = 0.f;
    f32x16_t acc[2][2];
#pragma unroll
    for (int mt = 0; mt < 2; ++mt)
#pragma unroll
        for (int ct = 0; ct < 2; ++ct)
#pragma unroll
            for (int e = 0; e < 16; ++e) acc[mt][ct][e] = 0.f;

    // B double-buffer: bq[p][u&1][ct*2+s], consume p=(u>>1)&1, load p^1 (j+2)
    bf16x8_t bq[2][2][4];
    float4 qaA[4], qaB[4];  // adj double-buffer (one chunk each)

    auto stageChunk = [&](int cidx, const float4 (&qa)[4], int buf) {
        unsigned short* sb = &sA[buf][0][0] + swoff;
#pragma unroll
        for (int ks = 0; ks < 4; ++ks) {
            const float4 v = qa[ks];
            float e0 = __expf(5.f * v.x);
            float e1 = __expf(5.f * v.y);
            float e2 = __expf(5.f * v.z);
            float e3 = __expf(5.f * v.w);
            const int gk = kbase + (cidx * 4 + ks) * 32 + skoff;
            if (gk + 0 == sgrow) e0 = 0.f;   // diagonal mask
            if (gk + 1 == sgrow) e1 = 0.f;
            if (gk + 2 == sgrow) e2 = 0.f;
            if (gk + 3 == sgrow) e3 = 0.f;
            rs += (e0 + e1) + (e2 + e3);
            uint2 p; p.x = pack2bf(e0, e1); p.y = pack2bf(e2, e3);
            *(uint2*)(sb + ks * (ROWS * ASTRIDE)) = p;
        }
    };

    auto phase = [&](int c, float4 (&qaPre)[4], const float4 (&qaStg)[4], int buf) {
        // adj prefetch for chunk c+2 (used next phase)
        if (c + 2 < NCH) {
#pragma unroll
            for (int ks = 0; ks < 4; ++ks)
                qaPre[ks] = *(const float4*)(adj_row + (size_t)((c + 2) * 4 + ks) * 32);
        }
        // stage chunk c+1 into the other buffer (overlaps this phase's MFMA)
        if (c + 1 < NCH) stageChunk(c + 1, qaStg, buf ^ 1);
        // compute chunk c
#pragma unroll
        for (int u = 0; u < 4; ++u) {
            const int j = c * 4 + u;
            int jn = j + 2; if (jn >= NIT) jn = 0;   // B prefetch 2 iters ahead
            // coalesced blob loads for jn -> slot [p^1][u&1]
            const unsigned short* bb = wb + (size_t)(jbase + jn) * 16384;
#pragma unroll
            for (int k4 = 0; k4 < 4; ++k4)
                bq[((u >> 1) ^ 1) & 1][u & 1][k4] = *(const bf16x8_t*)(bb + k4 * 512);
            // A fragments from LDS
            const unsigned short* sa = &sA[buf][u][0] + l31 * ASTRIDE + q * 8;
            bf16x8_t af[2][2];
#pragma unroll
            for (int mt = 0; mt < 2; ++mt)
#pragma unroll
                for (int s = 0; s < 2; ++s) {
                    const unsigned short* p = sa + mt * (32 * ASTRIDE) + s * 16;
                    bf16x4_t lo = *(const bf16x4_t*)p;
                    bf16x4_t hi = *(const bf16x4_t*)(p + 4);
                    af[mt][s] = __builtin_shufflevector(lo, hi, 0, 1, 2, 3, 4, 5, 6, 7);
                }
            __builtin_amdgcn_s_setprio(1);
#pragma unroll
            for (int s = 0; s < 2; ++s)
#pragma unroll
                for (int mt = 0; mt < 2; ++mt)
#pragma unroll
                    for (int ct = 0; ct < 2; ++ct)
                        acc[mt][ct] = MFMA32(af[mt][s], bq[(u >> 1) & 1][u & 1][ct * 2 + s], acc[mt][ct]);
            __builtin_amdgcn_s_setprio(0);
        }
        // lgkm-only barrier: LDS flushed, global-load queue stays in flight
        asm volatile("s_waitcnt lgkmcnt(0)\n\ts_barrier" ::: "memory");
    };

    // prologue: adj chunks 0,1; stage chunk 0; B j=0 -> bq[0][0], j=1 -> bq[0][1]
#pragma unroll
    for (int ks = 0; ks < 4; ++ks)
        qaA[ks] = *(const float4*)(adj_row + (size_t)ks * 32);
#pragma unroll
    for (int ks = 0; ks < 4; ++ks)
        qaB[ks] = *(const float4*)(adj_row + (size_t)(4 + ks) * 32);
    stageChunk(0, qaA, 0);
    {
        const unsigned short* b0 = wb + (size_t)(jbase + 0) * 16384;
        const unsigned short* b1 = wb + (size_t)(jbase + 1) * 16384;
#pragma unroll
        for (int k4 = 0; k4 < 4; ++k4) {
            bq[0][0][k4] = *(const bf16x8_t*)(b0 + k4 * 512);
            bq[0][1][k4] = *(const bf16x8_t*)(b1 + k4 * 512);
        }
    }
    asm volatile("s_waitcnt lgkmcnt(0)\n\ts_barrier" ::: "memory");

    for (int c0 = 0; c0 < NCH; c0 += 2) {
        phase(c0,     qaA, qaB, 0);
        phase(c0 + 1, qaB, qaA, 1);
    }

    // rowsum partial: 8 stager threads per row
    rs += __shfl_xor(rs, 1);
    rs += __shfl_xor(rs, 2);
    rs += __shfl_xor(rs, 4);
    if ((t & 7) == 0) sSp[h * 8192 + sgrow] = rs;

    // blocked store: per-wave 8 KB contiguous blob, full-line writes.
    // uint idx = ((mt*2+ct)*8+ip)*64 + lane holds rows rlo/rlo+1 where
    // rlo = mt*32 + 2*(ip&1) + 8*(ip>>1) + 4*q, col = ct*32 + (lane&31).
    unsigned* up = UpartB + (((size_t)h * 128 + rb) * 8 + w) * 2048 + lane;
#pragma unroll
    for (int mt = 0; mt < 2; ++mt)
#pragma unroll
        for (int ct = 0; ct < 2; ++ct)
#pragma unroll
            for (int ip = 0; ip < 8; ++ip)
                up[(size_t)(((mt * 2 + ct) * 8) + ip) * 64] =
                    pack2bf(acc[mt][ct][2 * ip], acc[mt][ct][2 * ip + 1]);
}

// ---------------------------------------------------------------------------
// finalize: sum 4 blocked bf16 partials, normalize; agg -> XcatN[:,256:512],
// kagg -> Kcat[:,256:512].
// grid = 1024 (128 rowblocks-of-64 x 8 col-groups-of-64), block = 256.
// ---------------------------------------------------------------------------
__global__ __launch_bounds__(256) void finalize_agg(
    const unsigned* __restrict__ UpartB, const float* __restrict__ sSp,
    unsigned* __restrict__ XcatN, unsigned* __restrict__ Kcat)
{
    __shared__ float sT[64][65];
    __shared__ float sInv[64];

    const int t = threadIdx.x;
    const int rb = blockIdx.x >> 3, wp = blockIdx.x & 7;
    const int row0 = rb * 64;

    if (t < 64) {
        const int r = row0 + t;
        sInv[t] = 1.f / (sSp[r] + sSp[8192 + r] + sSp[16384 + r] + sSp[24576 + r]);
    }

    // decode: thread t covers uint index i = t>>3, lanes l0..l0+7
    const int i = t >> 3;                 // 0..31
    const int l0 = (t & 7) * 8;           // 0..56
    const int mt = i >> 4, ct = (i >> 3) & 1, ip = i & 7;
    const int qq = l0 >> 5;
    const int rlo = mt * 32 + 2 * (ip & 1) + 8 * (ip >> 1) + 4 * qq;
    const int cbase = ct * 32 + (l0 & 31);

    float lo[8], hi[8];
#pragma unroll
    for (int j = 0; j < 8; ++j) { lo[j] = 0.f; hi[j] = 0.f; }
#pragma unroll
    for (int h = 0; h < 4; ++h) {
        const unsigned* src = UpartB + (((size_t)h * 128 + rb) * 8 + wp) * 2048
                              + (size_t)i * 64 + l0;
        const uint4 v0 = *(const uint4*)(src);
        const uint4 v1 = *(const uint4*)(src + 4);
        const unsigned vv[8] = { v0.x, v0.y, v0.z, v0.w, v1.x, v1.y, v1.z, v1.w };
#pragma unroll
        for (int j = 0; j < 8; ++j) { lo[j] += bflo(vv[j]); hi[j] += bfhi(vv[j]); }
    }
#pragma unroll
    for (int j = 0; j < 8; ++j) {
        sT[rlo][cbase + j]     = lo[j];
        sT[rlo + 1][cbase + j] = hi[j];
    }
    __syncthreads();

    // write: thread -> row = t>>2 (0..63), 16 f32 cols at (t&3)*16
    const int row = t >> 2, cg = (t & 3) * 16;
    const float inv = sInv[row];
    unsigned outv[8];
#pragma unroll
    for (int j = 0; j < 8; ++j)
        outv[j] = pack2bf(sT[row][cg + 2 * j] * inv, sT[row][cg + 2 * j + 1] * inv);
    unsigned* dst = (wp < 4 ? XcatN : Kcat)
                    + (size_t)(row0 + row) * 256 + 128 + (wp & 3) * 32 + (cg >> 1);
    *(uint4*)(dst)     = *(const uint4*)(outv);
    *(uint4*)(dst + 4) = *(const uint4*)(outv + 4);
}

// ---------------------------------------------------------------------------
// gemm_out (fused both problems): out[8192][256] f32 =
//   tanh(A[8192][512]bf16 @ Wt[256][512]^T + c).
// grid = 512 (2 problems x 256 Mtiles of 32), block = 256 (4 waves)
// -> 2 blocks/CU. Padded LDS (stride 36).
// ---------------------------------------------------------------------------
__global__ __launch_bounds__(256) void gemm_out(
    const unsigned short* __restrict__ Aa, const unsigned short* __restrict__ Wta,
    const float* __restrict__ ca,
    const unsigned short* __restrict__ Ab, const unsigned short* __restrict__ Wtb,
    const float* __restrict__ cb,
    float* __restrict__ outa, float* __restrict__ outb)
{
    __shared__ unsigned short sAm[32 * ASTRIDE];
    __shared__ unsigned short sB[256 * ASTRIDE];
    __shared__ float sBias[256];

    const int bid = blockIdx.x;
    const int prob = bid >> 8, tile = bid & 255;
    const unsigned short* A  = prob ? Ab  : Aa;
    const unsigned short* Wt = prob ? Wtb : Wta;
    const float* cvec        = prob ? cb  : ca;
    float* out               = prob ? outb : outa;

    const int t = threadIdx.x, w = t >> 6, lane = t & 63;
    const int m_lo = lane & 15, quad = lane >> 4;
    const int row0 = tile * 32;
    sBias[t] = cvec[t];

    f32x4_t acc[2][4];
#pragma unroll
    for (int a = 0; a < 2; ++a)
#pragma unroll
        for (int b = 0; b < 4; ++b)
#pragma unroll
            for (int e = 0; e < 4; ++e) acc[a][b][e] = 0.f;

    for (int ks = 0; ks < 16; ++ks) {
        const int k0 = ks * 32;
        __syncthreads();
        if (t < 128) {  // A tile 32x32
            bf16x8_t v = *(const bf16x8_t*)(A + (size_t)(row0 + (t >> 2)) * 512 + k0 + (t & 3) * 8);
            unsigned short* d = &sAm[(t >> 2) * ASTRIDE + (t & 3) * 8];
            *(bf16x4_t*)d       = __builtin_shufflevector(v, v, 0, 1, 2, 3);
            *(bf16x4_t*)(d + 4) = __builtin_shufflevector(v, v, 4, 5, 6, 7);
        }
        {               // B tile 256x32, thread t stages n-row t
            const unsigned short* src = Wt + (size_t)t * 512 + k0;
            unsigned short* d = &sB[t * ASTRIDE];
#pragma unroll
            for (int j = 0; j < 4; ++j) {
                bf16x8_t v = *(const bf16x8_t*)(src + j * 8);
                *(bf16x4_t*)(d + j * 8)     = __builtin_shufflevector(v, v, 0, 1, 2, 3);
                *(bf16x4_t*)(d + j * 8 + 4) = __builtin_shufflevector(v, v, 4, 5, 6, 7);
            }
        }
        __syncthreads();
        bf16x8_t a0, a1;
        {
            const unsigned short* p = &sAm[m_lo * ASTRIDE + quad * 8];
            bf16x4_t lo = *(const bf16x4_t*)p, hi = *(const bf16x4_t*)(p + 4);
            a0 = __builtin_shufflevector(lo, hi, 0, 1, 2, 3, 4, 5, 6, 7);
            p += 16 * ASTRIDE;
            lo = *(const bf16x4_t*)p; hi = *(const bf16x4_t*)(p + 4);
            a1 = __builtin_shufflevector(lo, hi, 0, 1, 2, 3, 4, 5, 6, 7);
        }
#pragma unroll
        for (int nt = 0; nt < 4; ++nt) {
            const unsigned short* p = &sB[(w * 64 + nt * 16 + m_lo) * ASTRIDE + quad * 8];
            bf16x4_t lo = *(const bf16x4_t*)p, hi = *(const bf16x4_t*)(p + 4);
            bf16x8_t b = __builtin_shufflevector(lo, hi, 0, 1, 2, 3, 4, 5, 6, 7);
            acc[0][nt] = MFMA16(a0, b, acc[0][nt]);
            acc[1][nt] = MFMA16(a1, b, acc[1][nt]);
        }
    }

#pragma unroll
    for (int mt = 0; mt < 2; ++mt)
#pragma unroll
        for (int nt = 0; nt < 4; ++nt) {
            const int col = w * 64 + nt * 16 + m_lo;
#pragma unroll
            for (int r = 0; r < 4; ++r) {
                const int row = row0 + mt * 16 + quad * 4 + r;
                out[(size_t)row * 256 + col] = tanhf(acc[mt][nt][r] + sBias[col]);
            }
        }
}

// ---------------------------------------------------------------------------
extern "C" void kernel_launch(void* const* d_in, const int* in_sizes, int n_in,
                              void* d_out, int out_size, void* d_ws, size_t ws_size,
                              hipStream_t stream) {
    const float* features = (const float*)d_in[0];
    const float* key      = (const float*)d_in[1];
    const float* adj      = (const float*)d_in[2];
    const float* W_d  = (const float*)d_in[3];
    const float* b_d  = (const float*)d_in[4];
    const float* W_o  = (const float*)d_in[5];
    const float* b_o  = (const float*)d_in[6];
    const float* W_a  = (const float*)d_in[7];
    const float* b_a  = (const float*)d_in[8];
    const float* W_ao = (const float*)d_in[9];
    const float* b_ao = (const float*)d_in[10];

    float* out1 = (float*)d_out;
    float* out2 = out1 + (size_t)8192 * 256;

    char* ws = (char*)d_ws;
    unsigned short* XcatN = (unsigned short*)(ws);                 // [8192][512] bf16, 8 MB
    unsigned short* Kcat  = (unsigned short*)(ws +  8388608);      // [8192][512] bf16, 8 MB
    unsigned short* Xtb   = (unsigned short*)(ws + 16777216);      // fragment blobs, 8 MB
    unsigned*       UpartB= (unsigned*)      (ws + 25165824);      // blocked [4][128][8][2048] u32, 32 MB
    float*          sSp   = (float*)         (ws + 58720256);      // [4][8192] f32
    unsigned short* W1t   = (unsigned short*)(ws + 58851328);      // [256][512] bf16
    unsigned short* W2t   = (unsigned short*)(ws + 59113472);      // [256][512] bf16
    float*          c1    = (float*)         (ws + 59375616);      // [256]
    float*          c2    = (float*)         (ws + 59376640);      // [256]

    dim3 blk(256);
    transpose_blob<<<dim3(256, 8), blk, 0, stream>>>(features, Xtb, 0);
    transpose_blob<<<dim3(256, 8), blk, 0, stream>>>(key, Xtb, 8);
    pack_half<<<4096, blk, 0, stream>>>(features, (unsigned*)XcatN);
    pack_half<<<4096, blk, 0, stream>>>(key, (unsigned*)Kcat);
    compose1<<<512, blk, 0, stream>>>(W_d, W_o, W1t);
    compose2<<<512, blk, 0, stream>>>(W_a, W_ao, W2t);
    biasC<<<1, blk, 0, stream>>>(b_d, b_o, b_a, b_ao, W_o, W_ao, c1, c2);

    exp_gemm<<<512, dim3(512), 0, stream>>>(adj, Xtb, UpartB, sSp);
    finalize_agg<<<1024, blk, 0, stream>>>(UpartB, sSp,
                                           (unsigned*)XcatN, (unsigned*)Kcat);

    gemm_out<<<512, blk, 0, stream>>>(XcatN, W1t, c1, Kcat, W2t, c2, out1, out2);
}

// Round 3
// 512.739 us; speedup vs baseline: 1.6286x; 1.6286x over previous
//
#include <hip/hip_runtime.h>
#include <stdint.h>
#include <math.h>

// ---------------------------------------------------------------------------
// GraphDistillOperatorWithEdgeWeight, N=8192, F=256, OUT=256
//
//   E_ij = exp(5*adj_ij), E_ii = 0 ; s_i = sum_j E_ij ; a = E/s
//   agg = a@feat ; kagg = a@key
//   out1 = tanh(Xcat @ W1 + c1),  Xcat=[feat|agg],  W1=[[W_o],[0]] - W_d@W_o
//   out2 = tanh(Kcat @ W2 + c2),  Kcat=[key|kagg],  W2=[[W_ao],[W_a@W_ao]]
//
// Round change (spill fix):
//  (1) exp_gemm __launch_bounds__(512, 2): one 8-wave block resident -> 256
//      combined VGPR+AGPR cap. Demand ~216 now FITS (round 2's (512,4) capped
//      at 64 arch VGPRs -> ~830 MB scratch writes in the K-loop).
//  (2) XCD-affine block decode: h = (bid&7)>>1 so each XCD's L2 keeps its
//      single 2 MB Xtb h-slice resident; rb spread over bid>>3 and bid&1.
// ---------------------------------------------------------------------------

typedef __attribute__((ext_vector_type(4)))  short bf16x4_t;
typedef __attribute__((ext_vector_type(8)))  short bf16x8_t;
typedef __attribute__((ext_vector_type(4)))  float f32x4_t;
typedef __attribute__((ext_vector_type(16))) float f32x16_t;

#define MFMA32(A, B, C) __builtin_amdgcn_mfma_f32_32x32x16_bf16(A, B, C, 0, 0, 0)
#define MFMA16(A, B, C) __builtin_amdgcn_mfma_f32_16x16x32_bf16(A, B, C, 0, 0, 0)

__device__ __forceinline__ unsigned short f2bf(float x) {
    union { float f; unsigned u; } c; c.f = x;
    unsigned u = c.u;
    return (unsigned short)((u + 0x7fffu + ((u >> 16) & 1u)) >> 16);  // RNE
}
__device__ __forceinline__ unsigned pack2bf(float a, float b) {
    return (unsigned)f2bf(a) | ((unsigned)f2bf(b) << 16);
}
__device__ __forceinline__ float bflo(unsigned u) {
    union { unsigned u; float f; } c; c.u = u << 16; return c.f;
}
__device__ __forceinline__ float bfhi(unsigned u) {
    union { unsigned u; float f; } c; c.u = u & 0xffff0000u; return c.f;
}

// ---------------------------------------------------------------------------
// transpose_blob: src[8192][256] f32 (row index = k) -> Xtb fragment blobs.
// Blob (j = k/32, c32): 1024 shorts, short idx = s*512 + lane*8 + e, where
// lane = ((k>>3)&1)*32 + (col&31), s = (k>>4)&1, e = k&7.  A wave's B-frag
// for (j, c32, s) is then ONE contiguous 1KB load at lane*16B.
// grid = (256 k-tiles, 8 col-tiles), block = 256.
// ---------------------------------------------------------------------------
__global__ __launch_bounds__(256) void transpose_blob(
    const float* __restrict__ src, unsigned short* __restrict__ Xtb, int c32base)
{
    __shared__ float tile[32][33];
    const int t = threadIdx.x;
    const int x = t & 31, y4 = (t >> 5) * 4;
    const int r0 = blockIdx.x * 32, c0 = blockIdx.y * 32;
#pragma unroll
    for (int i = 0; i < 4; ++i)
        tile[y4 + i][x] = src[(size_t)(r0 + y4 + i) * 256 + c0 + x];
    __syncthreads();
    // thread t writes shorts [t*4 .. t*4+3]: s = t>>7, lane = (t>>1)&63, e0 = (t&1)*4
    const int s = t >> 7, lane = (t >> 1) & 63, e0 = (t & 1) * 4;
    const int kl = s * 16 + (lane >> 5) * 8 + e0;   // k-local 0..31
    const int cl = lane & 31;                        // col-local
    unsigned short* blob = Xtb + ((size_t)blockIdx.x * 16 + (c0 >> 5) + c32base) * 1024;
    uint2 v;
    v.x = pack2bf(tile[kl][cl],     tile[kl + 1][cl]);
    v.y = pack2bf(tile[kl + 2][cl], tile[kl + 3][cl]);
    *(uint2*)(blob + t * 4) = v;
}

// dst row-major uint rows of 256 (=512 bf16 cols), fill cols 0..255.
__global__ __launch_bounds__(256) void pack_half(
    const float* __restrict__ src, unsigned* __restrict__ dst)
{
    const int idx = blockIdx.x * 256 + threadIdx.x;
    const int row = idx >> 7, cp = idx & 127;
    float2 v = *(const float2*)(src + (size_t)row * 256 + cp * 2);
    dst[(size_t)row * 256 + cp] = pack2bf(v.x, v.y);
}

// ---------------------------------------------------------------------------
// Weight composition (unchanged).
// ---------------------------------------------------------------------------
__global__ __launch_bounds__(256) void compose1(
    const float* __restrict__ W_d, const float* __restrict__ W_o,
    unsigned short* __restrict__ W1t)
{
    __shared__ float wrow[256];
    const int k = blockIdx.x, t = threadIdx.x;
    wrow[t] = W_d[(size_t)k * 256 + t];
    __syncthreads();
    float acc = 0.f;
#pragma unroll 8
    for (int m = 0; m < 256; ++m) acc = fmaf(wrow[m], W_o[(size_t)m * 256 + t], acc);
    const float v = (k < 256 ? W_o[(size_t)k * 256 + t] : 0.f) - acc;
    W1t[(size_t)t * 512 + k] = f2bf(v);
}

__global__ __launch_bounds__(256) void compose2(
    const float* __restrict__ W_a, const float* __restrict__ W_ao,
    unsigned short* __restrict__ W2t)
{
    __shared__ float wrow[256];
    const int k = blockIdx.x, t = threadIdx.x;
    float v;
    if (k < 256) {
        v = W_ao[(size_t)k * 256 + t];
    } else {
        wrow[t] = W_a[(size_t)(k - 256) * 256 + t];
        __syncthreads();
        float acc = 0.f;
#pragma unroll 8
        for (int m = 0; m < 256; ++m) acc = fmaf(wrow[m], W_ao[(size_t)m * 256 + t], acc);
        v = acc;
    }
    W2t[(size_t)t * 512 + k] = f2bf(v);
}

__global__ __launch_bounds__(256) void biasC(
    const float* __restrict__ b_d, const float* __restrict__ b_o,
    const float* __restrict__ b_a, const float* __restrict__ b_ao,
    const float* __restrict__ W_o, const float* __restrict__ W_ao,
    float* __restrict__ c1, float* __restrict__ c2)
{
    const int t = threadIdx.x;
    float a1 = 0.f, a2 = 0.f;
#pragma unroll 8
    for (int m = 0; m < 256; ++m) {
        a1 = fmaf(b_d[m], W_o [(size_t)m * 256 + t], a1);
        a2 = fmaf(b_a[m], W_ao[(size_t)m * 256 + t], a2);
    }
    c1[t] = b_o[t] - a1;
    c2[t] = b_ao[t] + a2;
}

// ---------------------------------------------------------------------------
// exp_gemm: Upart[h] = bf16( E_slice @ [feat|key] ), rowsum partials f32.
// grid = 512 (128 rowblocks x 4 K-split), block = 512 (8 waves).
// Block tile: 64 rows x 512 cols, K-slice 2048. Wave: 64 rows x 64 cols
// (2 mt x 2 ct of 32x32). LDS 36 KB. launch_bounds(512,2) -> 256-reg cap,
// one resident block (no spill). XCD-affine h.
// ---------------------------------------------------------------------------
#define ROWS 64
#define KSLICE 2048
#define NIT 64      // k-steps of 32 per K-slice
#define NCH 16      // chunks of 4 k-steps
#define ASTRIDE 36  // padded LDS row stride (shorts)

__global__ __launch_bounds__(512, 2) void exp_gemm(
    const float* __restrict__ adj, const unsigned short* __restrict__ Xtb,
    unsigned* __restrict__ UpartB, float* __restrict__ sSp)
{
    __shared__ unsigned short sA[2][4][ROWS * ASTRIDE];  // 36 KB

    const int t = threadIdx.x;
    const int w = t >> 6, lane = t & 63, q = lane >> 5, l31 = lane & 31;
    // XCD-affine decode: xcd = bid&7 (dispatch round-robins XCDs), each XCD
    // owns ONE h-slice -> its 2 MB Xtb slice stays hot in the XCD-private L2.
    const int xcd = blockIdx.x & 7;
    const int h = xcd >> 1;
    const int rb = ((blockIdx.x >> 3) << 1) | (xcd & 1);
    const int row0 = rb * ROWS;
    const int kbase = h * KSLICE, jbase = h * (KSLICE / 32);

    // stager role: row srow (t>>3, 0..63), k-offset skoff (8 threads/row)
    const int srow = t >> 3, skoff = (t & 7) * 4;
    const int sgrow = row0 + srow;
    const float* adj_row = adj + (size_t)sgrow * 8192 + kbase + skoff;
    const int swoff = srow * ASTRIDE + skoff;

    // wave w owns cols w*64..w*64+63 (c32 = 2w, 2w+1)
    const unsigned short* wb = Xtb + (size_t)(2 * w) * 1024 + lane * 8;

    float rs = 0.f;
    f32x16_t acc[2][2];
#pragma unroll
    for (int mt = 0; mt < 2; ++mt)
#pragma unroll
        for (int ct = 0; ct < 2; ++ct)
#pragma unroll
            for (int e = 0; e < 16; ++e) acc[mt][ct][e] = 0.f;

    // B double-buffer: bq[p][u&1][ct*2+s], consume p=(u>>1)&1, load p^1 (j+2)
    bf16x8_t bq[2][2][4];
    float4 qaA[4], qaB[4];  // adj double-buffer (one chunk each)

    auto stageChunk = [&](int cidx, const float4 (&qa)[4], int buf) {
        unsigned short* sb = &sA[buf][0][0] + swoff;
#pragma unroll
        for (int ks = 0; ks < 4; ++ks) {
            const float4 v = qa[ks];
            float e0 = __expf(5.f * v.x);
            float e1 = __expf(5.f * v.y);
            float e2 = __expf(5.f * v.z);
            float e3 = __expf(5.f * v.w);
            const int gk = kbase + (cidx * 4 + ks) * 32 + skoff;
            if (gk + 0 == sgrow) e0 = 0.f;   // diagonal mask
            if (gk + 1 == sgrow) e1 = 0.f;
            if (gk + 2 == sgrow) e2 = 0.f;
            if (gk + 3 == sgrow) e3 = 0.f;
            rs += (e0 + e1) + (e2 + e3);
            uint2 p; p.x = pack2bf(e0, e1); p.y = pack2bf(e2, e3);
            *(uint2*)(sb + ks * (ROWS * ASTRIDE)) = p;
        }
    };

    auto phase = [&](int c, float4 (&qaPre)[4], const float4 (&qaStg)[4], int buf) {
        // adj prefetch for chunk c+2 (used next phase)
        if (c + 2 < NCH) {
#pragma unroll
            for (int ks = 0; ks < 4; ++ks)
                qaPre[ks] = *(const float4*)(adj_row + (size_t)((c + 2) * 4 + ks) * 32);
        }
        // stage chunk c+1 into the other buffer (overlaps this phase's MFMA)
        if (c + 1 < NCH) stageChunk(c + 1, qaStg, buf ^ 1);
        // compute chunk c
#pragma unroll
        for (int u = 0; u < 4; ++u) {
            const int j = c * 4 + u;
            int jn = j + 2; if (jn >= NIT) jn = 0;   // B prefetch 2 iters ahead
            // coalesced blob loads for jn -> slot [p^1][u&1]
            const unsigned short* bb = wb + (size_t)(jbase + jn) * 16384;
#pragma unroll
            for (int k4 = 0; k4 < 4; ++k4)
                bq[((u >> 1) ^ 1) & 1][u & 1][k4] = *(const bf16x8_t*)(bb + k4 * 512);
            // A fragments from LDS
            const unsigned short* sa = &sA[buf][u][0] + l31 * ASTRIDE + q * 8;
            bf16x8_t af[2][2];
#pragma unroll
            for (int mt = 0; mt < 2; ++mt)
#pragma unroll
                for (int s = 0; s < 2; ++s) {
                    const unsigned short* p = sa + mt * (32 * ASTRIDE) + s * 16;
                    bf16x4_t lo = *(const bf16x4_t*)p;
                    bf16x4_t hi = *(const bf16x4_t*)(p + 4);
                    af[mt][s] = __builtin_shufflevector(lo, hi, 0, 1, 2, 3, 4, 5, 6, 7);
                }
            __builtin_amdgcn_s_setprio(1);
#pragma unroll
            for (int s = 0; s < 2; ++s)
#pragma unroll
                for (int mt = 0; mt < 2; ++mt)
#pragma unroll
                    for (int ct = 0; ct < 2; ++ct)
                        acc[mt][ct] = MFMA32(af[mt][s], bq[(u >> 1) & 1][u & 1][ct * 2 + s], acc[mt][ct]);
            __builtin_amdgcn_s_setprio(0);
        }
        // lgkm-only barrier: LDS flushed, global-load queue stays in flight
        asm volatile("s_waitcnt lgkmcnt(0)\n\ts_barrier" ::: "memory");
    };

    // prologue: adj chunks 0,1; stage chunk 0; B j=0 -> bq[0][0], j=1 -> bq[0][1]
#pragma unroll
    for (int ks = 0; ks < 4; ++ks)
        qaA[ks] = *(const float4*)(adj_row + (size_t)ks * 32);
#pragma unroll
    for (int ks = 0; ks < 4; ++ks)
        qaB[ks] = *(const float4*)(adj_row + (size_t)(4 + ks) * 32);
    stageChunk(0, qaA, 0);
    {
        const unsigned short* b0 = wb + (size_t)(jbase + 0) * 16384;
        const unsigned short* b1 = wb + (size_t)(jbase + 1) * 16384;
#pragma unroll
        for (int k4 = 0; k4 < 4; ++k4) {
            bq[0][0][k4] = *(const bf16x8_t*)(b0 + k4 * 512);
            bq[0][1][k4] = *(const bf16x8_t*)(b1 + k4 * 512);
        }
    }
    asm volatile("s_waitcnt lgkmcnt(0)\n\ts_barrier" ::: "memory");

    for (int c0 = 0; c0 < NCH; c0 += 2) {
        phase(c0,     qaA, qaB, 0);
        phase(c0 + 1, qaB, qaA, 1);
    }

    // rowsum partial: 8 stager threads per row
    rs += __shfl_xor(rs, 1);
    rs += __shfl_xor(rs, 2);
    rs += __shfl_xor(rs, 4);
    if ((t & 7) == 0) sSp[h * 8192 + sgrow] = rs;

    // blocked store: per-wave 8 KB contiguous blob, full-line writes.
    // uint idx = ((mt*2+ct)*8+ip)*64 + lane holds rows rlo/rlo+1 where
    // rlo = mt*32 + 2*(ip&1) + 8*(ip>>1) + 4*q, col = ct*32 + (lane&31).
    unsigned* up = UpartB + (((size_t)h * 128 + rb) * 8 + w) * 2048 + lane;
#pragma unroll
    for (int mt = 0; mt < 2; ++mt)
#pragma unroll
        for (int ct = 0; ct < 2; ++ct)
#pragma unroll
            for (int ip = 0; ip < 8; ++ip)
                up[(size_t)(((mt * 2 + ct) * 8) + ip) * 64] =
                    pack2bf(acc[mt][ct][2 * ip], acc[mt][ct][2 * ip + 1]);
}

// ---------------------------------------------------------------------------
// finalize: sum 4 blocked bf16 partials, normalize; agg -> XcatN[:,256:512],
// kagg -> Kcat[:,256:512].
// grid = 1024 (128 rowblocks-of-64 x 8 col-groups-of-64), block = 256.
// ---------------------------------------------------------------------------
__global__ __launch_bounds__(256) void finalize_agg(
    const unsigned* __restrict__ UpartB, const float* __restrict__ sSp,
    unsigned* __restrict__ XcatN, unsigned* __restrict__ Kcat)
{
    __shared__ float sT[64][65];
    __shared__ float sInv[64];

    const int t = threadIdx.x;
    const int rb = blockIdx.x >> 3, wp = blockIdx.x & 7;
    const int row0 = rb * 64;

    if (t < 64) {
        const int r = row0 + t;
        sInv[t] = 1.f / (sSp[r] + sSp[8192 + r] + sSp[16384 + r] + sSp[24576 + r]);
    }

    // decode: thread t covers uint index i = t>>3, lanes l0..l0+7
    const int i = t >> 3;                 // 0..31
    const int l0 = (t & 7) * 8;           // 0..56
    const int mt = i >> 4, ct = (i >> 3) & 1, ip = i & 7;
    const int qq = l0 >> 5;
    const int rlo = mt * 32 + 2 * (ip & 1) + 8 * (ip >> 1) + 4 * qq;
    const int cbase = ct * 32 + (l0 & 31);

    float lo[8], hi[8];
#pragma unroll
    for (int j = 0; j < 8; ++j) { lo[j] = 0.f; hi[j] = 0.f; }
#pragma unroll
    for (int h = 0; h < 4; ++h) {
        const unsigned* src = UpartB + (((size_t)h * 128 + rb) * 8 + wp) * 2048
                              + (size_t)i * 64 + l0;
        const uint4 v0 = *(const uint4*)(src);
        const uint4 v1 = *(const uint4*)(src + 4);
        const unsigned vv[8] = { v0.x, v0.y, v0.z, v0.w, v1.x, v1.y, v1.z, v1.w };
#pragma unroll
        for (int j = 0; j < 8; ++j) { lo[j] += bflo(vv[j]); hi[j] += bfhi(vv[j]); }
    }
#pragma unroll
    for (int j = 0; j < 8; ++j) {
        sT[rlo][cbase + j]     = lo[j];
        sT[rlo + 1][cbase + j] = hi[j];
    }
    __syncthreads();

    // write: thread -> row = t>>2 (0..63), 16 f32 cols at (t&3)*16
    const int row = t >> 2, cg = (t & 3) * 16;
    const float inv = sInv[row];
    unsigned outv[8];
#pragma unroll
    for (int j = 0; j < 8; ++j)
        outv[j] = pack2bf(sT[row][cg + 2 * j] * inv, sT[row][cg + 2 * j + 1] * inv);
    unsigned* dst = (wp < 4 ? XcatN : Kcat)
                    + (size_t)(row0 + row) * 256 + 128 + (wp & 3) * 32 + (cg >> 1);
    *(uint4*)(dst)     = *(const uint4*)(outv);
    *(uint4*)(dst + 4) = *(const uint4*)(outv + 4);
}

// ---------------------------------------------------------------------------
// gemm_out (fused both problems): out[8192][256] f32 =
//   tanh(A[8192][512]bf16 @ Wt[256][512]^T + c).
// grid = 512 (2 problems x 256 Mtiles of 32), block = 256 (4 waves)
// -> 2 blocks/CU. Padded LDS (stride 36).
// ---------------------------------------------------------------------------
__global__ __launch_bounds__(256) void gemm_out(
    const unsigned short* __restrict__ Aa, const unsigned short* __restrict__ Wta,
    const float* __restrict__ ca,
    const unsigned short* __restrict__ Ab, const unsigned short* __restrict__ Wtb,
    const float* __restrict__ cb,
    float* __restrict__ outa, float* __restrict__ outb)
{
    __shared__ unsigned short sAm[32 * ASTRIDE];
    __shared__ unsigned short sB[256 * ASTRIDE];
    __shared__ float sBias[256];

    const int bid = blockIdx.x;
    const int prob = bid >> 8, tile = bid & 255;
    const unsigned short* A  = prob ? Ab  : Aa;
    const unsigned short* Wt = prob ? Wtb : Wta;
    const float* cvec        = prob ? cb  : ca;
    float* out               = prob ? outb : outa;

    const int t = threadIdx.x, w = t >> 6, lane = t & 63;
    const int m_lo = lane & 15, quad = lane >> 4;
    const int row0 = tile * 32;
    sBias[t] = cvec[t];

    f32x4_t acc[2][4];
#pragma unroll
    for (int a = 0; a < 2; ++a)
#pragma unroll
        for (int b = 0; b < 4; ++b)
#pragma unroll
            for (int e = 0; e < 4; ++e) acc[a][b][e] = 0.f;

    for (int ks = 0; ks < 16; ++ks) {
        const int k0 = ks * 32;
        __syncthreads();
        if (t < 128) {  // A tile 32x32
            bf16x8_t v = *(const bf16x8_t*)(A + (size_t)(row0 + (t >> 2)) * 512 + k0 + (t & 3) * 8);
            unsigned short* d = &sAm[(t >> 2) * ASTRIDE + (t & 3) * 8];
            *(bf16x4_t*)d       = __builtin_shufflevector(v, v, 0, 1, 2, 3);
            *(bf16x4_t*)(d + 4) = __builtin_shufflevector(v, v, 4, 5, 6, 7);
        }
        {               // B tile 256x32, thread t stages n-row t
            const unsigned short* src = Wt + (size_t)t * 512 + k0;
            unsigned short* d = &sB[t * ASTRIDE];
#pragma unroll
            for (int j = 0; j < 4; ++j) {
                bf16x8_t v = *(const bf16x8_t*)(src + j * 8);
                *(bf16x4_t*)(d + j * 8)     = __builtin_shufflevector(v, v, 0, 1, 2, 3);
                *(bf16x4_t*)(d + j * 8 + 4) = __builtin_shufflevector(v, v, 4, 5, 6, 7);
            }
        }
        __syncthreads();
        bf16x8_t a0, a1;
        {
            const unsigned short* p = &sAm[m_lo * ASTRIDE + quad * 8];
            bf16x4_t lo = *(const bf16x4_t*)p, hi = *(const bf16x4_t*)(p + 4);
            a0 = __builtin_shufflevector(lo, hi, 0, 1, 2, 3, 4, 5, 6, 7);
            p += 16 * ASTRIDE;
            lo = *(const bf16x4_t*)p; hi = *(const bf16x4_t*)(p + 4);
            a1 = __builtin_shufflevector(lo, hi, 0, 1, 2, 3, 4, 5, 6, 7);
        }
#pragma unroll
        for (int nt = 0; nt < 4; ++nt) {
            const unsigned short* p = &sB[(w * 64 + nt * 16 + m_lo) * ASTRIDE + quad * 8];
            bf16x4_t lo = *(const bf16x4_t*)p, hi = *(const bf16x4_t*)(p + 4);
            bf16x8_t b = __builtin_shufflevector(lo, hi, 0, 1, 2, 3, 4, 5, 6, 7);
            acc[0][nt] = MFMA16(a0, b, acc[0][nt]);
            acc[1][nt] = MFMA16(a1, b, acc[1][nt]);
        }
    }

#pragma unroll
    for (int mt = 0; mt < 2; ++mt)
#pragma unroll
        for (int nt = 0; nt < 4; ++nt) {
            const int col = w * 64 + nt * 16 + m_lo;
#pragma unroll
            for (int r = 0; r < 4; ++r) {
                const int row = row0 + mt * 16 + quad * 4 + r;
                out[(size_t)row * 256 + col] = tanhf(acc[mt][nt][r] + sBias[col]);
            }
        }
}

// ---------------------------------------------------------------------------
extern "C" void kernel_launch(void* const* d_in, const int* in_sizes, int n_in,
                              void* d_out, int out_size, void* d_ws, size_t ws_size,
                              hipStream_t stream) {
    const float* features = (const float*)d_in[0];
    const float* key      = (const float*)d_in[1];
    const float* adj      = (const float*)d_in[2];
    const float* W_d  = (const float*)d_in[3];
    const float* b_d  = (const float*)d_in[4];
    const float* W_o  = (const float*)d_in[5];
    const float* b_o  = (const float*)d_in[6];
    const float* W_a  = (const float*)d_in[7];
    const float* b_a  = (const float*)d_in[8];
    const float* W_ao = (const float*)d_in[9];
    const float* b_ao = (const float*)d_in[10];

    float* out1 = (float*)d_out;
    float* out2 = out1 + (size_t)8192 * 256;

    char* ws = (char*)d_ws;
    unsigned short* XcatN = (unsigned short*)(ws);                 // [8192][512] bf16, 8 MB
    unsigned short* Kcat  = (unsigned short*)(ws +  8388608);      // [8192][512] bf16, 8 MB
    unsigned short* Xtb   = (unsigned short*)(ws + 16777216);      // fragment blobs, 8 MB
    unsigned*       UpartB= (unsigned*)      (ws + 25165824);      // blocked [4][128][8][2048] u32, 32 MB
    float*          sSp   = (float*)         (ws + 58720256);      // [4][8192] f32
    unsigned short* W1t   = (unsigned short*)(ws + 58851328);      // [256][512] bf16
    unsigned short* W2t   = (unsigned short*)(ws + 59113472);      // [256][512] bf16
    float*          c1    = (float*)         (ws + 59375616);      // [256]
    float*          c2    = (float*)         (ws + 59376640);      // [256]

    dim3 blk(256);
    transpose_blob<<<dim3(256, 8), blk, 0, stream>>>(features, Xtb, 0);
    transpose_blob<<<dim3(256, 8), blk, 0, stream>>>(key, Xtb, 8);
    pack_half<<<4096, blk, 0, stream>>>(features, (unsigned*)XcatN);
    pack_half<<<4096, blk, 0, stream>>>(key, (unsigned*)Kcat);
    compose1<<<512, blk, 0, stream>>>(W_d, W_o, W1t);
    compose2<<<512, blk, 0, stream>>>(W_a, W_ao, W2t);
    biasC<<<1, blk, 0, stream>>>(b_d, b_o, b_a, b_ao, W_o, W_ao, c1, c2);

    exp_gemm<<<512, dim3(512), 0, stream>>>(adj, Xtb, UpartB, sSp);
    finalize_agg<<<1024, blk, 0, stream>>>(UpartB, sSp,
                                           (unsigned*)XcatN, (unsigned*)Kcat);

    gemm_out<<<512, blk, 0, stream>>>(XcatN, W1t, c1, Kcat, W2t, c2, out1, out2);
}